// Round 4
// baseline (128.638 us; speedup 1.0000x reference)
//
#include <hip/hip_runtime.h>
#include <math.h>

// Problem constants
#define B 32
#define T 32
#define L 196
#define S 512
#define D 512

// -------------------------------------------------------------------------
// K1: w1v[s] = sum_d W1[s,d] * V[d]. One wave per row, float4 dot + shuffle
// reduce. grid = 128 blocks x 4 waves = 512 rows.
// -------------------------------------------------------------------------
__global__ void k_w1v(const float* __restrict__ W1, const float* __restrict__ V,
                      float* __restrict__ w1v) {
    const int wave = threadIdx.x >> 6, lane = threadIdx.x & 63;
    const int row  = blockIdx.x * 4 + wave;
    const float4* r  = (const float4*)(W1 + (size_t)row * D);
    const float4* v4 = (const float4*)V;
    float p0 = 0.f, p1 = 0.f;
    {
        float4 a = r[lane], bb = v4[lane];
        p0 = a.x * bb.x + a.y * bb.y + a.z * bb.z + a.w * bb.w;
        float4 c = r[64 + lane], dd = v4[64 + lane];
        p1 = c.x * dd.x + c.y * dd.y + c.z * dd.z + c.w * dd.w;
    }
    float p = p0 + p1;
    for (int off = 32; off; off >>= 1) p += __shfl_down(p, off);
    if (lane == 0) w1v[row] = p;
}

// -------------------------------------------------------------------------
// K2: sc[b*L+l] = x_static[b,l,:] . w1v  — one wave per (b,l) row.
// rows = B*L = 6272, 4 waves/block -> 1568 blocks.
// -------------------------------------------------------------------------
__global__ void k_scores(const float* __restrict__ xs, const float* __restrict__ w1v,
                         float* __restrict__ sc) {
    const int wave = threadIdx.x >> 6, lane = threadIdx.x & 63;
    const int row  = blockIdx.x * 4 + wave;
    if (row >= B * L) return;
    const float4* r  = (const float4*)(xs + (size_t)row * S);
    const float4* v4 = (const float4*)w1v;
    float4 a = r[lane], bb = v4[lane];
    float4 c = r[64 + lane], dd = v4[64 + lane];
    float p = (a.x * bb.x + a.y * bb.y + a.z * bb.z + a.w * bb.w) +
              (c.x * dd.x + c.y * dd.y + c.z * dd.z + c.w * dd.w);
    for (int off = 32; off; off >>= 1) p += __shfl_down(p, off);
    if (lane == 0) sc[row] = p;
}

// -------------------------------------------------------------------------
// K3: per-(b, 64-col s-chunk) block: redundant softmax over sc[b,:] (cheap),
// then ctx[b,s] = sum_l attn[l]*xs[b,l,s]. 4 l-subsets x 64 s-lanes with
// 8-deep unroll (8 loads in flight). grid = (S/64=8, B) = 256 blocks.
// -------------------------------------------------------------------------
__global__ void k_ctx(const float* __restrict__ xs, const float* __restrict__ sc,
                      float* __restrict__ ctx) {
    __shared__ float attn[256];
    __shared__ float red[8];
    __shared__ float part[4][64];
    const int b = blockIdx.y, s0 = blockIdx.x * 64, tid = threadIdx.x;
    const int lane = tid & 63, wave = tid >> 6;

    float v = (tid < L) ? sc[b * L + tid] : -1e30f;
    float m = v;
    for (int off = 32; off; off >>= 1) m = fmaxf(m, __shfl_down(m, off));
    if (lane == 0) red[wave] = m;
    __syncthreads();
    m = fmaxf(fmaxf(red[0], red[1]), fmaxf(red[2], red[3]));
    float e = (tid < L) ? expf(v - m) : 0.f;
    attn[tid] = e;
    float ssum = e;
    for (int off = 32; off; off >>= 1) ssum += __shfl_down(ssum, off);
    if (lane == 0) red[4 + wave] = ssum;
    __syncthreads();
    const float inv = 1.f / (red[4] + red[5] + red[6] + red[7]);

    const float* xb = xs + (size_t)b * L * S + s0 + lane;
    float a[8];
#pragma unroll
    for (int u = 0; u < 8; ++u) a[u] = 0.f;
    int l = wave;                       // waves interleave l (stride 4)
    for (int g = 0; g < 6; ++g) {       // 6 groups x 8 = 48 iters each
#pragma unroll
        for (int u = 0; u < 8; ++u)
            a[u] = fmaf(attn[l + u * 4], xb[(size_t)(l + u * 4) * S], a[u]);
        l += 32;
    }
    // remainder: l = wave + 192 (< 196 for wave 0..3)
    a[0] = fmaf(attn[l], xb[(size_t)l * S], a[0]);
    float acc = ((a[0] + a[1]) + (a[2] + a[3])) + ((a[4] + a[5]) + (a[6] + a[7]));
    part[wave][lane] = acc;
    __syncthreads();
    if (wave == 0)
        ctx[b * S + s0 + lane] =
            (part[0][lane] + part[1][lane] + part[2][lane] + part[3][lane]) * inv;
}

// -------------------------------------------------------------------------
// K4: cp[b,d] = b3[d] + sum_s ctx[b,s] * W3[D+s, d]. 64 d-lanes x 4
// contiguous 128-s chunks, 8-deep unroll (8 loads in flight), LDS reduce.
// grid = (D/64=8, B) = 256 blocks.
// -------------------------------------------------------------------------
__global__ void k_cproj(const float* __restrict__ ctx, const float* __restrict__ W3,
                        const float* __restrict__ b3, float* __restrict__ cp) {
    __shared__ float c[S];
    __shared__ float part[4][64];
    const int b = blockIdx.y, d0 = blockIdx.x * 64, tid = threadIdx.x;
    const int lane = tid & 63, sub = tid >> 6;
    for (int i = tid; i < S; i += 256) c[i] = ctx[b * S + i];
    __syncthreads();

    const float* w = W3 + (size_t)D * D + d0 + lane;  // lower half, col d0+lane
    float a[8];
#pragma unroll
    for (int u = 0; u < 8; ++u) a[u] = 0.f;
    const int sbase = sub * 128;
    for (int s = sbase; s < sbase + 128; s += 8) {
#pragma unroll
        for (int u = 0; u < 8; ++u)
            a[u] = fmaf(c[s + u], w[(size_t)(s + u) * D], a[u]);
    }
    float acc = ((a[0] + a[1]) + (a[2] + a[3])) + ((a[4] + a[5]) + (a[6] + a[7]));
    part[sub][lane] = acc;
    __syncthreads();
    if (sub == 0)
        cp[b * D + d0 + lane] = part[0][lane] + part[1][lane] + part[2][lane] +
                                part[3][lane] + b3[d0 + lane];
}

// -------------------------------------------------------------------------
// K5: out[b,t,d] = x[b,t,:] . W3[:D,d] + cp[b,d].
// No LDS: the x-tile operand is wave-uniform (indices depend only on
// blockIdx + loop counters), so it compiles to s_load -> SGPR broadcast on
// the scalar pipe (free FMA operand, dual-issues with VALU). Inner loop per
// k: 1 coalesced W3 load + 8 SGPR-sourced FMAs. 256 d-cols x 8 t-rows per
// block, grid = (2, 4, 32) = 256 blocks (1/CU), VALU-floor ~3.4 us.
// -------------------------------------------------------------------------
__global__ __launch_bounds__(256) void k_out(const float* __restrict__ x,
                                             const float* __restrict__ W3,
                                             const float* __restrict__ cp,
                                             float* __restrict__ out) {
    const int b = blockIdx.z, t0 = blockIdx.y * 8, d0 = blockIdx.x * 256;
    const int d = d0 + threadIdx.x;
    const float* xb = x + ((size_t)b * T + t0) * D;   // wave-uniform base
    const float* wp = W3 + d;

    float a[8];
#pragma unroll
    for (int i = 0; i < 8; ++i) a[i] = 0.f;

#pragma unroll 8
    for (int k = 0; k < D; ++k) {
        const float w = wp[(size_t)k * D];            // coalesced VMEM
#pragma unroll
        for (int i = 0; i < 8; ++i)
            a[i] = fmaf(xb[(size_t)i * D + k], w, a[i]);  // uniform -> SGPR
    }
    const float c = cp[b * D + d];
    float* ob = out + ((size_t)b * T + t0) * D + d;
#pragma unroll
    for (int i = 0; i < 8; ++i) ob[(size_t)i * D] = a[i] + c;
}

extern "C" void kernel_launch(void* const* d_in, const int* in_sizes, int n_in,
                              void* d_out, int out_size, void* d_ws, size_t ws_size,
                              hipStream_t stream) {
    const float* x  = (const float*)d_in[0];   // [B,T,D]
    const float* xs = (const float*)d_in[1];   // [B,L,S]
    const float* W1 = (const float*)d_in[3];   // [S,D]
    const float* W3 = (const float*)d_in[5];   // [D+S, D]
    const float* b3 = (const float*)d_in[7];   // [D]
    const float* V  = (const float*)d_in[8];   // [D,1]
    float* out = (float*)d_out;

    // Workspace layout (floats). cp overlays w1v+sc which are dead by then.
    float* ws  = (float*)d_ws;
    float* w1v = ws;                   // [0, 512)
    float* sc  = ws + 512;             // [512, 6784)  B*L = 6272
    float* cp  = ws;                   // [0, 16384)   written after w1v/sc dead
    float* ctx = ws + 16384;           // [16384, 32768)

    k_w1v   <<<dim3(S / 4),       dim3(256), 0, stream>>>(W1, V, w1v);
    k_scores<<<dim3(B * L / 4),   dim3(256), 0, stream>>>(xs, w1v, sc);
    k_ctx   <<<dim3(S / 64, B),   dim3(256), 0, stream>>>(xs, sc, ctx);
    k_cproj <<<dim3(D / 64, B),   dim3(256), 0, stream>>>(ctx, W3, b3, cp);
    k_out   <<<dim3(2, T / 8, B), dim3(256), 0, stream>>>(x, W3, cp, out);
}

// Round 5
// 110.478 us; speedup vs baseline: 1.1644x; 1.1644x over previous
//
#include <hip/hip_runtime.h>
#include <math.h>

// Problem constants
#define B 32
#define T 32
#define L 196
#define S 512
#define D 512

// -------------------------------------------------------------------------
// K1: w1v[s] = sum_d W1[s,d] * V[d]. One wave per row, float4 dot + shuffle
// reduce. grid = 128 blocks x 4 waves = 512 rows.
// -------------------------------------------------------------------------
__global__ void k_w1v(const float* __restrict__ W1, const float* __restrict__ V,
                      float* __restrict__ w1v) {
    const int wave = threadIdx.x >> 6, lane = threadIdx.x & 63;
    const int row  = blockIdx.x * 4 + wave;
    const float4* r  = (const float4*)(W1 + (size_t)row * D);
    const float4* v4 = (const float4*)V;
    float p0 = 0.f, p1 = 0.f;
    {
        float4 a = r[lane], bb = v4[lane];
        p0 = a.x * bb.x + a.y * bb.y + a.z * bb.z + a.w * bb.w;
        float4 c = r[64 + lane], dd = v4[64 + lane];
        p1 = c.x * dd.x + c.y * dd.y + c.z * dd.z + c.w * dd.w;
    }
    float p = p0 + p1;
    for (int off = 32; off; off >>= 1) p += __shfl_down(p, off);
    if (lane == 0) w1v[row] = p;
}

// -------------------------------------------------------------------------
// K2: sc[b*L+l] = x_static[b,l,:] . w1v  — one wave per (b,l) row.
// rows = B*L = 6272, 4 waves/block -> 1568 blocks.
// -------------------------------------------------------------------------
__global__ void k_scores(const float* __restrict__ xs, const float* __restrict__ w1v,
                         float* __restrict__ sc) {
    const int wave = threadIdx.x >> 6, lane = threadIdx.x & 63;
    const int row  = blockIdx.x * 4 + wave;
    if (row >= B * L) return;
    const float4* r  = (const float4*)(xs + (size_t)row * S);
    const float4* v4 = (const float4*)w1v;
    float4 a = r[lane], bb = v4[lane];
    float4 c = r[64 + lane], dd = v4[64 + lane];
    float p = (a.x * bb.x + a.y * bb.y + a.z * bb.z + a.w * bb.w) +
              (c.x * dd.x + c.y * dd.y + c.z * dd.z + c.w * dd.w);
    for (int off = 32; off; off >>= 1) p += __shfl_down(p, off);
    if (lane == 0) sc[row] = p;
}

// -------------------------------------------------------------------------
// K3: per-(b, 64-col s-chunk) block: redundant softmax over sc[b,:] (cheap),
// then ctx[b,s] = sum_l attn[l]*xs[b,l,s]. 4 l-subsets x 64 s-lanes with
// 8-deep unroll (8 loads in flight). grid = (S/64=8, B) = 256 blocks.
// -------------------------------------------------------------------------
__global__ void k_ctx(const float* __restrict__ xs, const float* __restrict__ sc,
                      float* __restrict__ ctx) {
    __shared__ float attn[256];
    __shared__ float red[8];
    __shared__ float part[4][64];
    const int b = blockIdx.y, s0 = blockIdx.x * 64, tid = threadIdx.x;
    const int lane = tid & 63, wave = tid >> 6;

    float v = (tid < L) ? sc[b * L + tid] : -1e30f;
    float m = v;
    for (int off = 32; off; off >>= 1) m = fmaxf(m, __shfl_down(m, off));
    if (lane == 0) red[wave] = m;
    __syncthreads();
    m = fmaxf(fmaxf(red[0], red[1]), fmaxf(red[2], red[3]));
    float e = (tid < L) ? expf(v - m) : 0.f;
    attn[tid] = e;
    float ssum = e;
    for (int off = 32; off; off >>= 1) ssum += __shfl_down(ssum, off);
    if (lane == 0) red[4 + wave] = ssum;
    __syncthreads();
    const float inv = 1.f / (red[4] + red[5] + red[6] + red[7]);

    const float* xb = xs + (size_t)b * L * S + s0 + lane;
    float a[8];
#pragma unroll
    for (int u = 0; u < 8; ++u) a[u] = 0.f;
    int l = wave;                       // waves interleave l (stride 4)
    for (int g = 0; g < 6; ++g) {       // 6 groups x 8 = 48 iters each
#pragma unroll
        for (int u = 0; u < 8; ++u)
            a[u] = fmaf(attn[l + u * 4], xb[(size_t)(l + u * 4) * S], a[u]);
        l += 32;
    }
    // remainder: l = wave + 192 (< 196 for wave 0..3)
    a[0] = fmaf(attn[l], xb[(size_t)l * S], a[0]);
    float acc = ((a[0] + a[1]) + (a[2] + a[3])) + ((a[4] + a[5]) + (a[6] + a[7]));
    part[wave][lane] = acc;
    __syncthreads();
    if (wave == 0)
        ctx[b * S + s0 + lane] =
            (part[0][lane] + part[1][lane] + part[2][lane] + part[3][lane]) * inv;
}

// -------------------------------------------------------------------------
// K4: cp[b,d] = b3[d] + sum_s ctx[b,s] * W3[D+s, d]. 64 d-lanes x 4
// contiguous 128-s chunks, 8-deep unroll (8 loads in flight), LDS reduce.
// grid = (D/64=8, B) = 256 blocks.
// -------------------------------------------------------------------------
__global__ void k_cproj(const float* __restrict__ ctx, const float* __restrict__ W3,
                        const float* __restrict__ b3, float* __restrict__ cp) {
    __shared__ float c[S];
    __shared__ float part[4][64];
    const int b = blockIdx.y, d0 = blockIdx.x * 64, tid = threadIdx.x;
    const int lane = tid & 63, sub = tid >> 6;
    for (int i = tid; i < S; i += 256) c[i] = ctx[b * S + i];
    __syncthreads();

    const float* w = W3 + (size_t)D * D + d0 + lane;  // lower half, col d0+lane
    float a[8];
#pragma unroll
    for (int u = 0; u < 8; ++u) a[u] = 0.f;
    const int sbase = sub * 128;
    for (int s = sbase; s < sbase + 128; s += 8) {
#pragma unroll
        for (int u = 0; u < 8; ++u)
            a[u] = fmaf(c[s + u], w[(size_t)(s + u) * D], a[u]);
    }
    float acc = ((a[0] + a[1]) + (a[2] + a[3])) + ((a[4] + a[5]) + (a[6] + a[7]));
    part[sub][lane] = acc;
    __syncthreads();
    if (sub == 0)
        cp[b * D + d0 + lane] = part[0][lane] + part[1][lane] + part[2][lane] +
                                part[3][lane] + b3[d0 + lane];
}

// -------------------------------------------------------------------------
// K5: out[b,t,d] = x[b,t,:] . W3[:D,d] + cp[b,d].
// Latency-bound fix: t-tile 4 -> 512 blocks (2/CU, 8 waves/CU), x staged
// TRANSPOSED in LDS (xlt[k][4], one broadcast ds_read_b128 per k — avoids
// the s_load/SGPR serialization trap of R4), k-loop unrolled x16 so each
// wave keeps 16 W3 loads in flight. L2-traffic floor ~7.4 us.
// -------------------------------------------------------------------------
__global__ __launch_bounds__(256) void k_out(const float* __restrict__ x,
                                             const float* __restrict__ W3,
                                             const float* __restrict__ cp,
                                             float* __restrict__ out) {
    __shared__ float xlt[D * 4];        // [k][t] transposed, 8 KB
    const int b = blockIdx.z, t0 = blockIdx.y * 4, d0 = blockIdx.x * 256;
    const int tid = threadIdx.x;
    const float* xb = x + ((size_t)b * T + t0) * D;
    for (int idx = tid; idx < 4 * D; idx += 256) {
        const int i = idx >> 9;         // t within tile (global read coalesced in k)
        const int k = idx & (D - 1);
        xlt[k * 4 + i] = xb[(size_t)i * D + k];
    }
    __syncthreads();

    const int d = d0 + tid;
    const float* wp = W3 + d;
    float a0 = 0.f, a1 = 0.f, a2 = 0.f, a3 = 0.f;
#pragma unroll 16
    for (int k = 0; k < D; ++k) {
        const float w  = wp[(size_t)k * D];             // coalesced VMEM
        const float4 xv = *(const float4*)&xlt[k * 4];  // broadcast ds_read_b128
        a0 = fmaf(xv.x, w, a0);
        a1 = fmaf(xv.y, w, a1);
        a2 = fmaf(xv.z, w, a2);
        a3 = fmaf(xv.w, w, a3);
    }
    const float c = cp[b * D + d];
    float* ob = out + ((size_t)b * T + t0) * D + d;
    ob[0 * D] = a0 + c;
    ob[1 * D] = a1 + c;
    ob[2 * D] = a2 + c;
    ob[3 * D] = a3 + c;
}

extern "C" void kernel_launch(void* const* d_in, const int* in_sizes, int n_in,
                              void* d_out, int out_size, void* d_ws, size_t ws_size,
                              hipStream_t stream) {
    const float* x  = (const float*)d_in[0];   // [B,T,D]
    const float* xs = (const float*)d_in[1];   // [B,L,S]
    const float* W1 = (const float*)d_in[3];   // [S,D]
    const float* W3 = (const float*)d_in[5];   // [D+S, D]
    const float* b3 = (const float*)d_in[7];   // [D]
    const float* V  = (const float*)d_in[8];   // [D,1]
    float* out = (float*)d_out;

    // Workspace layout (floats). cp overlays w1v+sc which are dead by then.
    float* ws  = (float*)d_ws;
    float* w1v = ws;                   // [0, 512)
    float* sc  = ws + 512;             // [512, 6784)  B*L = 6272
    float* cp  = ws;                   // [0, 16384)   written after w1v/sc dead
    float* ctx = ws + 16384;           // [16384, 32768)

    k_w1v   <<<dim3(S / 4),       dim3(256), 0, stream>>>(W1, V, w1v);
    k_scores<<<dim3(B * L / 4),   dim3(256), 0, stream>>>(xs, w1v, sc);
    k_ctx   <<<dim3(S / 64, B),   dim3(256), 0, stream>>>(xs, sc, ctx);
    k_cproj <<<dim3(D / 64, B),   dim3(256), 0, stream>>>(ctx, W3, b3, cp);
    k_out   <<<dim3(2, T / 4, B), dim3(256), 0, stream>>>(x, W3, cp, out);
}